// Round 6
// baseline (353.887 us; speedup 1.0000x reference)
//
#include <hip/hip_runtime.h>
#include <math.h>

#define BB 8
#define CC 512
#define LL 4096
#define DQK 64

typedef short short8 __attribute__((ext_vector_type(8)));
typedef unsigned short ushort4v __attribute__((ext_vector_type(4)));
typedef unsigned short ushort8v __attribute__((ext_vector_type(8)));
typedef float floatx4 __attribute__((ext_vector_type(4)));
typedef float floatx2 __attribute__((ext_vector_type(2)));
typedef float floatx16 __attribute__((ext_vector_type(16)));
typedef unsigned int uint4v __attribute__((ext_vector_type(4)));

__device__ __forceinline__ unsigned short f2bf(float f) {
    union { float f; unsigned u; } v; v.f = f;
    unsigned r = v.u + 0x7fffu + ((v.u >> 16) & 1u);
    return (unsigned short)(r >> 16);
}

// async global->LDS DMA, 16B per lane. LDS dest is wave-uniform base + lane*16.
__device__ __forceinline__ void load_lds16(const void* gptr, void* lptr) {
    __builtin_amdgcn_global_load_lds(
        (const __attribute__((address_space(1))) unsigned int*)gptr,
        (__attribute__((address_space(3))) unsigned int*)lptr, 16, 0, 0);
}

__device__ __forceinline__ unsigned cvt_pk_bf16(float lo, float hi) {
    unsigned r;
    asm("v_cvt_pk_bf16_f32 %0, %1, %2" : "=v"(r) : "v"(lo), "v"(hi));
    return r;
}

// ---------------- weight cast ----------------
__global__ void k_castw(const float* __restrict__ wq, const float* __restrict__ wk,
                        const float* __restrict__ wv,
                        unsigned short* __restrict__ wqb, unsigned short* __restrict__ wkb,
                        unsigned short* __restrict__ wvb) {
    int i = blockIdx.x * 256 + threadIdx.x;   // grid covers 262144
    if (i < DQK * CC) { wqb[i] = f2bf(wq[i]); wkb[i] = f2bf(wk[i]); }
    wvb[i] = f2bf(wv[i]);
}

// ---------------- fused transpose + cast + q/k/v projection (round-6 rebuild) ----------------
// Theory: prep was latency-bound at 2 waves/SIMD. Fixes:
//  * 32-l tiles (grid 128x8=1024): xtile 32 KB, no wstage -> 4 blocks/CU = 4 waves/SIMD.
//  * mfma 32x32x16: per-wave 32d x 32l output; W (A/B from regs) covers 32 rows ->
//    xtile b128 reads and MFMA count HALVED per FLOP vs 16x16x32.
//  * unified fragment addressing: row = lane&31, 8 contiguous k at (lane>>5)*8, for BOTH
//    W (global) and x (LDS, granule-XOR swizzled). V vs Q/K differ only in operand order:
//      V:  D = W*x  -> row=d, col=lane&31=l  -> u16 stores coalesced along l (64B segs)
//      QK: D = x*W  -> row=l, col=lane&31=d  -> u16 stores coalesced along d (64B segs)
//    No wstage LDS round-trip at all.
//  * acc parity split (acc0/acc1) breaks the 32-deep serial MFMA chain; W 8-frag dbuf.
// Steps: 4 V-steps (128 d each: wave w -> d = step*128 + w*32) + 1 QK-step
// (waves 0,1 -> q d 0..63; waves 2,3 -> k d 0..63).
__global__ __launch_bounds__(256) void k_prep(const float* __restrict__ x,
                                              const unsigned short* __restrict__ wqb,
                                              const unsigned short* __restrict__ wkb,
                                              const unsigned short* __restrict__ wvb,
                                              const float* __restrict__ bq,
                                              const float* __restrict__ bk,
                                              const float* __restrict__ bv,
                                              unsigned short* __restrict__ qout,
                                              unsigned short* __restrict__ kout,
                                              unsigned short* __restrict__ vout) {
    int l0 = blockIdx.x * 32;
    int b  = blockIdx.y;
    int tid = threadIdx.x;
    int w = tid >> 6, lane = tid & 63;
    int l32 = lane & 31, lh = lane >> 5;
    __shared__ unsigned short xtile[32 * 512];

    // ---- stage: x[c][l] slab (512c x 32l) -> xtile[l][swizzled c granules] ----
    {
        int cset = tid >> 4;      // 0..15: 32-c group
        int lp   = tid & 15;      // l-pair: l = 2lp, 2lp+1
        const float* xb = x + ((size_t)b * CC + cset * 32) * LL + l0 + 2 * lp;
        floatx2 A[8], B[8];
        auto ldg8 = [&](floatx2* d, int cg) {
#pragma unroll
            for (int k = 0; k < 8; ++k) d[k] = *(const floatx2*)(xb + (size_t)(cg * 8 + k) * LL);
        };
        auto wr8 = [&](floatx2* s, int cg) {
            int gi = cset * 4 + cg;           // granule index 0..63
#pragma unroll
            for (int e = 0; e < 2; ++e) {
                int l  = 2 * lp + e;
                int pg = (gi & 56) | ((gi ^ (l & 7)) & 7);
                uint4v u = { cvt_pk_bf16(s[0][e], s[1][e]), cvt_pk_bf16(s[2][e], s[3][e]),
                             cvt_pk_bf16(s[4][e], s[5][e]), cvt_pk_bf16(s[6][e], s[7][e]) };
                *(uint4v*)(xtile + l * 512 + pg * 8) = u;
            }
        };
        ldg8(A, 0); ldg8(B, 1);
        wr8(A, 0);  ldg8(A, 2);
        wr8(B, 1);  ldg8(B, 3);
        wr8(A, 2);  wr8(B, 3);
    }
    __syncthreads();

    // x-fragment bases: addr = l32*512 + (ks>>2)*64 + xoff[ks&3]  (u16 units)
    const unsigned short* xbase[4];
#pragma unroll
    for (int j = 0; j < 4; ++j) {
        int low = (((j * 2 + lh) ^ (l32 & 7)) & 7) * 8;
        xbase[j] = xtile + l32 * 512 + low;
    }

    for (int step = 0; step < 5; ++step) {
        bool isV = (step < 4);
        int dbase = isV ? (step * 128 + w * 32) : ((w & 1) * 32);
        const unsigned short* wsrc = isV ? wvb : ((w >> 1) ? wkb : wqb);
        const unsigned short* wrow = wsrc + (size_t)(dbase + l32) * CC + lh * 8;

        short8 wfA[8], wfB[8];
#pragma unroll
        for (int k = 0; k < 8; ++k) wfA[k] = *(const short8*)(wrow + k * 32);

        floatx16 acc0, acc1;
#pragma unroll
        for (int r = 0; r < 16; ++r) { acc0[r] = 0.f; acc1[r] = 0.f; }

#pragma unroll
        for (int kg = 0; kg < 4; ++kg) {
            short8* cur = (kg & 1) ? wfB : wfA;
            short8* nxt = (kg & 1) ? wfA : wfB;
            if (kg < 3) {
#pragma unroll
                for (int k = 0; k < 8; ++k)
                    nxt[k] = *(const short8*)(wrow + (kg + 1) * 256 + k * 32);
            }
#pragma unroll
            for (int kk = 0; kk < 8; ++kk) {
                int ks = kg * 8 + kk;
                short8 xf = *(const short8*)(xbase[ks & 3] + (ks >> 2) * 64);
                if (isV) {
                    if (ks & 1) acc1 = __builtin_amdgcn_mfma_f32_32x32x16_bf16(cur[kk], xf, acc1, 0, 0, 0);
                    else        acc0 = __builtin_amdgcn_mfma_f32_32x32x16_bf16(cur[kk], xf, acc0, 0, 0, 0);
                } else {
                    if (ks & 1) acc1 = __builtin_amdgcn_mfma_f32_32x32x16_bf16(xf, cur[kk], acc1, 0, 0, 0);
                    else        acc0 = __builtin_amdgcn_mfma_f32_32x32x16_bf16(xf, cur[kk], acc0, 0, 0, 0);
                }
            }
        }

        if (isV) {
            // D: row=d-offset=(r&3)+8*(r>>2)+4*lh, col=l32=l. Coalesced u16 stores along l.
#pragma unroll
            for (int r = 0; r < 16; ++r) {
                int d = dbase + (r & 3) + 8 * (r >> 2) + 4 * lh;
                float v = acc0[r] + acc1[r] + bv[d];
                vout[((size_t)b * CC + d) * LL + l0 + l32] = f2bf(v);
            }
        } else {
            // D: row=l-offset, col=l32=d. Coalesced u16 stores along d.
            const float* bias = (w >> 1) ? bk : bq;
            float sc = (w >> 1) ? 1.0f : 1.4426950408889634f;   // LOG2E folded into q
            float bd = bias[dbase + l32];
            unsigned short* dst = ((w >> 1) ? kout : qout) + (size_t)b * LL * DQK + dbase + l32;
#pragma unroll
            for (int r = 0; r < 16; ++r) {
                int l = l0 + (r & 3) + 8 * (r >> 2) + 4 * lh;
                float v = (acc0[r] + acc1[r] + bd) * sc;
                dst[(size_t)l * DQK] = f2bf(v);
            }
        }
    }
}

// ---------------- fused flash attention (round-2 schedule, proven ~179 us; FROZEN) ----------------
// grid: (L/128, B, C/256). 4 waves x 32 q-rows.
//  * swapped QK^T, in-register P repack (cvt_pk + permlane), ones-MFMA denominator
//  * j-tile split into two independent 32-j halves for MFMA/VALU overlap
//  * single __syncthreads-drained double-buffer (counted-vmcnt variant REGRESSED)
//  * XCD-aware remap: 32 blocks sharing one (b,z) K/V set -> same XCD L2
// Known structural bound: ~6.5 GB LDS traffic at ~60 B/cyc/CU (~70% of b128 ceiling).
__global__ __launch_bounds__(256, 2) void k_attn(const unsigned short* __restrict__ q,
                                                 const unsigned short* __restrict__ kws,
                                                 const unsigned short* __restrict__ vws,
                                                 const float* __restrict__ x,
                                                 const float* __restrict__ gamma,
                                                 float* __restrict__ out) {
    // bijective remap: hw bid -> (bx, by, bz); group g=(b,z) of 32 blocks -> XCD g&7
    int bid = blockIdx.x + 32 * blockIdx.y + 256 * blockIdx.z;
    int x8  = bid & 7;
    int ii  = bid >> 3;                  // 0..63
    int wg  = (x8 + 8 * (ii >> 5)) * 32 + (ii & 31);
    int i0 = (wg & 31) * 128;
    int b  = (wg >> 5) & 7;
    int c0 = (wg >> 8) * 256;

    int tid = threadIdx.x;
    int w = tid >> 6, lane = tid & 63;
    int lane16 = lane & 15, g = lane >> 4;
    int iw = i0 + w * 32;

    __shared__ unsigned short kt[2][64 * 64];    // 2 x  8 KB: K tile [j][d], swizzled
    __shared__ unsigned short vt[2][256 * 64];   // 2 x 32 KB: V tile [c][j], swizzled

    // Q fragments (B-operand of swapped QK^T: col=lane16 -> q-row i)
    short8 qf[2][2];
#pragma unroll
    for (int m = 0; m < 2; ++m) {
        const unsigned short* qrow = q + ((size_t)b * LL + iw + m * 16 + lane16) * DQK + g * 8;
        qf[m][0] = *(const short8*)(qrow);
        qf[m][1] = *(const short8*)(qrow + 32);
    }

    const unsigned short* kglob = kws + (size_t)b * LL * DQK;
    const unsigned short* vglob = vws + ((size_t)b * CC + c0) * LL;
    int gr    = (tid & 7) ^ ((tid >> 3) & 7);
    int koff0 = (tid >> 3) * DQK + gr * 8;
    int voff0 = (tid >> 3) * LL  + gr * 8;

    // fragment read offsets (ushort units) within one buffer
    int kro[2], vro[2];
#pragma unroll
    for (int kk = 0; kk < 2; ++kk) {
        int sw = (kk * 4 + g) ^ (lane16 & 7);
        kro[kk] = lane16 * 64 + sw * 8;
        vro[kk] = lane16 * 64 + sw * 8;
    }

    short8 ones;
#pragma unroll
    for (int j = 0; j < 8; ++j) ones[j] = (short)0x3f80;   // bf16 1.0

    floatx4 O[2][16];
#pragma unroll
    for (int m = 0; m < 2; ++m)
#pragma unroll
        for (int nt = 0; nt < 16; ++nt) O[m][nt] = {0.f, 0.f, 0.f, 0.f};
    floatx4 Ol[2];
#pragma unroll
    for (int m = 0; m < 2; ++m) Ol[m] = {0.f, 0.f, 0.f, 0.f};

    auto stage = [&](int j0n, int buf) {
        const unsigned short* ks = kglob + j0n * DQK + koff0;
        unsigned short* kd = &kt[buf][tid * 8];
        load_lds16(ks,        kd);
        load_lds16(ks + 2048, kd + 2048);
        const unsigned short* vs = vglob + j0n + voff0;
        unsigned short* vd = &vt[buf][tid * 8];
#pragma unroll
        for (int i = 0; i < 8; ++i)
            load_lds16(vs + i * 131072, vd + i * 2048);
    };

    // exp + in-register repack + ones-MFMA for one 32-j half
    auto softmax_half = [&](floatx4 (&Sh)[2][2], short8 (&paD)[2]) {
#pragma unroll
        for (int m = 0; m < 2; ++m) {
            float e0[4], e1[4];
#pragma unroll
            for (int r = 0; r < 4; ++r) {
                e0[r] = __builtin_amdgcn_exp2f(Sh[m][0][r]);
                e1[r] = __builtin_amdgcn_exp2f(Sh[m][1][r]);
            }
            unsigned A0 = cvt_pk_bf16(e0[0], e0[1]);
            unsigned A1 = cvt_pk_bf16(e0[2], e0[3]);
            unsigned B0 = cvt_pk_bf16(e1[0], e1[1]);
            unsigned B1 = cvt_pk_bf16(e1[2], e1[3]);
            asm("v_permlane32_swap_b32 %0, %1" : "+v"(A0), "+v"(B0));
            asm("v_permlane16_swap_b32 %0, %1" : "+v"(A0), "+v"(B0));
            asm("v_permlane32_swap_b32 %0, %1" : "+v"(A1), "+v"(B1));
            asm("v_permlane16_swap_b32 %0, %1" : "+v"(A1), "+v"(B1));
            uint4v pw = { A0, A1, B0, B1 };
            paD[m] = *(short8*)&pw;
            Ol[m] = __builtin_amdgcn_mfma_f32_16x16x32_bf16(paD[m], ones, Ol[m], 0, 0, 0);
        }
    };

    stage(0, 0);
    int cur = 0;
    for (int j0 = 0; j0 < LL; j0 += 64) {
        __syncthreads();                      // buf[cur] DMA drained; prev reads of buf[cur^1] done
        if (j0 + 64 < LL) stage(j0 + 64, cur ^ 1);

        const unsigned short* kbp = kt[cur];
        const unsigned short* vbp = vt[cur];

        floatx4 Sa[2][2], Sb[2][2];
#pragma unroll
        for (int m = 0; m < 2; ++m)
#pragma unroll
            for (int nt = 0; nt < 2; ++nt) { Sa[m][nt] = {0.f,0.f,0.f,0.f}; Sb[m][nt] = {0.f,0.f,0.f,0.f}; }

        // ---- S half0 (j 0..31) ----
        short8 ka0 = *(const short8*)(kbp + kro[0]);
        short8 ka1 = *(const short8*)(kbp + kro[1]);
        short8 kb0 = *(const short8*)(kbp + kro[0] + 1024);
        short8 kb1 = *(const short8*)(kbp + kro[1] + 1024);
#pragma unroll
        for (int m = 0; m < 2; ++m) {
            Sa[m][0] = __builtin_amdgcn_mfma_f32_16x16x32_bf16(ka0, qf[m][0], Sa[m][0], 0, 0, 0);
            Sa[m][0] = __builtin_amdgcn_mfma_f32_16x16x32_bf16(ka1, qf[m][1], Sa[m][0], 0, 0, 0);
            Sa[m][1] = __builtin_amdgcn_mfma_f32_16x16x32_bf16(kb0, qf[m][0], Sa[m][1], 0, 0, 0);
            Sa[m][1] = __builtin_amdgcn_mfma_f32_16x16x32_bf16(kb1, qf[m][1], Sa[m][1], 0, 0, 0);
        }
        // ---- S half1 (j 32..63) ----
        short8 kc0 = *(const short8*)(kbp + kro[0] + 2048);
        short8 kc1 = *(const short8*)(kbp + kro[1] + 2048);
        short8 kd0 = *(const short8*)(kbp + kro[0] + 3072);
        short8 kd1 = *(const short8*)(kbp + kro[1] + 3072);
#pragma unroll
        for (int m = 0; m < 2; ++m) {
            Sb[m][0] = __builtin_amdgcn_mfma_f32_16x16x32_bf16(kc0, qf[m][0], Sb[m][0], 0, 0, 0);
            Sb[m][0] = __builtin_amdgcn_mfma_f32_16x16x32_bf16(kc1, qf[m][1], Sb[m][0], 0, 0, 0);
            Sb[m][1] = __builtin_amdgcn_mfma_f32_16x16x32_bf16(kd0, qf[m][0], Sb[m][1], 0, 0, 0);
            Sb[m][1] = __builtin_amdgcn_mfma_f32_16x16x32_bf16(kd1, qf[m][1], Sb[m][1], 0, 0, 0);
        }

        short8 pa0[2], pa1[2];
        softmax_half(Sa, pa0);     // independent of Sb MFMAs -> scheduler overlaps

        // ---- PV half0, first 8 c-tiles ----
        __builtin_amdgcn_s_setprio(1);
#pragma unroll
        for (int nt = 0; nt < 8; ++nt) {
            short8 vf = *(const short8*)(vbp + vro[0] + nt * 1024);
#pragma unroll
            for (int m = 0; m < 2; ++m)
                O[m][nt] = __builtin_amdgcn_mfma_f32_16x16x32_bf16(pa0[m], vf, O[m][nt], 0, 0, 0);
        }
        __builtin_amdgcn_s_setprio(0);

        softmax_half(Sb, pa1);     // overlaps PV-half0 tail / next PV issue

        __builtin_amdgcn_s_setprio(1);
#pragma unroll
        for (int nt = 8; nt < 16; ++nt) {
            short8 vf = *(const short8*)(vbp + vro[0] + nt * 1024);
#pragma unroll
            for (int m = 0; m < 2; ++m)
                O[m][nt] = __builtin_amdgcn_mfma_f32_16x16x32_bf16(pa0[m], vf, O[m][nt], 0, 0, 0);
        }
#pragma unroll
        for (int nt = 0; nt < 16; ++nt) {
            short8 vf = *(const short8*)(vbp + vro[1] + nt * 1024);
#pragma unroll
            for (int m = 0; m < 2; ++m)
                O[m][nt] = __builtin_amdgcn_mfma_f32_16x16x32_bf16(pa1[m], vf, O[m][nt], 0, 0, 0);
        }
        __builtin_amdgcn_s_setprio(0);
        cur ^= 1;
    }

    // ---- epilogue: out = gamma * O / l + x ----
    float linv[2][4];
#pragma unroll
    for (int m = 0; m < 2; ++m)
#pragma unroll
        for (int r = 0; r < 4; ++r) linv[m][r] = 1.f / Ol[m][r];

    float gam = gamma[0];
#pragma unroll
    for (int m = 0; m < 2; ++m)
#pragma unroll
        for (int nt = 0; nt < 16; ++nt) {
            int c = c0 + nt * 16 + lane16;
            size_t base = ((size_t)b * CC + c) * LL + iw + m * 16 + g * 4;
            floatx4 xv = *(const floatx4*)(x + base);
            floatx4 o;
#pragma unroll
            for (int r = 0; r < 4; ++r) o[r] = gam * (O[m][nt][r] * linv[m][r]) + xv[r];
            *(floatx4*)(out + base) = o;
        }
}

extern "C" void kernel_launch(void* const* d_in, const int* in_sizes, int n_in,
                              void* d_out, int out_size, void* d_ws, size_t ws_size,
                              hipStream_t stream) {
    const float* x     = (const float*)d_in[0];
    const float* Wq    = (const float*)d_in[1];
    const float* bq    = (const float*)d_in[2];
    const float* Wk    = (const float*)d_in[3];
    const float* bk    = (const float*)d_in[4];
    const float* Wv    = (const float*)d_in[5];
    const float* bv    = (const float*)d_in[6];
    const float* gamma = (const float*)d_in[7];
    float* out = (float*)d_out;

    unsigned short* qb  = (unsigned short*)d_ws;          // B*L*64     =  2,097,152
    unsigned short* kb  = qb  + (size_t)BB * LL * DQK;
    unsigned short* vb  = kb  + (size_t)BB * LL * DQK;    // B*C*L      = 16,777,216
    unsigned short* wqb = vb  + (size_t)BB * CC * LL;     // 32768
    unsigned short* wkb = wqb + (size_t)DQK * CC;
    unsigned short* wvb = wkb + (size_t)DQK * CC;         // 262144

    k_castw<<<dim3((CC * CC) / 256), 256, 0, stream>>>(Wq, Wk, Wv, wqb, wkb, wvb);
    k_prep<<<dim3(LL / 32, BB), 256, 0, stream>>>(x, wqb, wkb, wvb, bq, bk, bv, qb, kb, vb);
    k_attn<<<dim3(LL / 128, BB, CC / 256), 256, 0, stream>>>(qb, kb, vb, x, gamma, out);
}